// Round 1
// baseline (32.987 us; speedup 1.0000x reference)
//
#include <hip/hip_runtime.h>

// MeanPooling: xs [B=16, T=2048, D=1024] fp32, xs_len [B] int (64 or 32), out [B, D] fp32.
// out[b][d] = sum_{t < len_b} xs[b][t][d] / len_b

#define B_ 16
#define T_ 2048
#define D_ 1024
#define CH 32            // rows (t) per slice handled by one block
#define NS (T_ / CH)     // 64 slices per batch sample

__global__ __launch_bounds__(256) void MeanPooling_kernel(
    const float* __restrict__ xs,
    const void* __restrict__ len_ptr,
    float* __restrict__ out)
{
    const int bid = blockIdx.x;
    const int b = bid / NS;
    const int s = bid % NS;

    // Sniff xs_len dtype: if stored as int64, element 0 read as i64 is in [1, T_].
    // If stored as int32, the first i64 read = len0 | (len1 << 32) >= 2^32 (len1 >= 1).
    long long len;
    {
        const long long v0 = ((const long long*)len_ptr)[0];
        if (v0 >= 1 && v0 <= (long long)T_) {
            len = ((const long long*)len_ptr)[b];
        } else {
            len = (long long)((const int*)len_ptr)[b];
        }
    }
    if (len < 1) len = 1;
    if (len > T_) len = T_;

    const int t0 = s * CH;
    int tend = t0 + CH;
    if ((long long)tend > len) tend = (int)len;
    if (t0 >= tend) return;  // slice fully past this sample's length

    const int tid = threadIdx.x;  // 256 threads x float4 = 1024 floats = full D row

    const float4* src = (const float4*)xs + ((long)b * T_ + t0) * (D_ / 4) + tid;
    float4 acc = make_float4(0.f, 0.f, 0.f, 0.f);

    #pragma unroll 4
    for (int t = t0; t < tend; ++t) {
        float4 v = *src;
        src += (D_ / 4);
        acc.x += v.x; acc.y += v.y; acc.z += v.z; acc.w += v.w;
    }

    const float inv = 1.0f / (float)len;
    float* o = out + (long)b * D_ + tid * 4;
    atomicAdd(o + 0, acc.x * inv);
    atomicAdd(o + 1, acc.y * inv);
    atomicAdd(o + 2, acc.z * inv);
    atomicAdd(o + 3, acc.w * inv);
}

extern "C" void kernel_launch(void* const* d_in, const int* in_sizes, int n_in,
                              void* d_out, int out_size, void* d_ws, size_t ws_size,
                              hipStream_t stream)
{
    const float* xs = (const float*)d_in[0];
    const void* xs_len = d_in[1];
    float* out = (float*)d_out;

    // Zero accumulator target each call (harness poisons once, never re-zeroes).
    hipMemsetAsync(d_out, 0, (size_t)out_size * sizeof(float), stream);

    dim3 grid(B_ * NS);   // 1024 blocks
    dim3 block(256);
    MeanPooling_kernel<<<grid, block, 0, stream>>>(xs, xs_len, out);
}

// Round 2
// 22.447 us; speedup vs baseline: 1.4695x; 1.4695x over previous
//
#include <hip/hip_runtime.h>

// MeanPooling: xs [B=16, T=2048, D=1024] fp32, xs_len [B] (int64 or int32), out [B, D] fp32.
// out[b][d] = sum_{t < len_b} xs[b][t][d] / len_b
//
// Two-phase, no atomics, no memset:
//   K1: block (b, s) sums rows [s*32, min((s+1)*32, len_b)) into ws[(b*64+s)][0:1024]
//   K2: block (b, c) reduces the nact = ceil(len_b/32) valid slices for D-chunk c,
//       scales by 1/len_b, writes out. ws slots beyond nact are never read.

#define B_ 16
#define T_ 2048
#define D_ 1024
#define CH 32            // rows (t) per slice
#define NS (T_ / CH)     // 64 slices per sample

__device__ __forceinline__ long long read_len(const void* len_ptr, int b)
{
    // Sniff xs_len dtype: if stored as int64, element 0 read as i64 is in [1, T_].
    // If stored as int32, the first i64 read = len0 | (len1 << 32) >= 2^32 (len1 >= 1).
    long long len;
    const long long v0 = ((const long long*)len_ptr)[0];
    if (v0 >= 1 && v0 <= (long long)T_) {
        len = ((const long long*)len_ptr)[b];
    } else {
        len = (long long)((const int*)len_ptr)[b];
    }
    if (len < 1) len = 1;
    if (len > T_) len = T_;
    return len;
}

__global__ __launch_bounds__(256) void mp_partial(
    const float* __restrict__ xs,
    const void* __restrict__ len_ptr,
    float* __restrict__ ws)
{
    const int bid = blockIdx.x;
    const int b = bid >> 6;          // / NS
    const int s = bid & (NS - 1);    // % NS

    const long long len = read_len(len_ptr, b);

    const int t0 = s * CH;
    int tend = t0 + CH;
    if ((long long)tend > len) tend = (int)len;
    if (t0 >= tend) return;          // slice fully past this sample's length

    const int tid = threadIdx.x;     // 256 threads x float4 = 1024 floats = full D row

    const float4* src = (const float4*)xs + ((long)b * T_ + t0) * (D_ / 4) + tid;
    float4 acc = make_float4(0.f, 0.f, 0.f, 0.f);

    #pragma unroll 4
    for (int t = t0; t < tend; ++t) {
        float4 v = *src;
        src += (D_ / 4);
        acc.x += v.x; acc.y += v.y; acc.z += v.z; acc.w += v.w;
    }

    ((float4*)ws)[(long)bid * (D_ / 4) + tid] = acc;
}

__global__ __launch_bounds__(256) void mp_reduce(
    const float* __restrict__ ws,
    const void* __restrict__ len_ptr,
    float* __restrict__ out)
{
    const int b = blockIdx.x >> 2;   // 4 blocks per sample
    const int c = blockIdx.x & 3;    // D-chunk: 256 floats = 64 float4
    const int lane = threadIdx.x & 63;
    const int w = threadIdx.x >> 6;  // 4 waves stride the slices

    const long long len = read_len(len_ptr, b);
    const int nact = (int)((len + (CH - 1)) >> 5);   // ceil(len / 32), in [1, 64]

    const int d4 = c * 64 + lane;    // float4 index in [0, 256)
    const float4* wsp = (const float4*)ws;

    float4 acc = make_float4(0.f, 0.f, 0.f, 0.f);
    #pragma unroll 4
    for (int s = w; s < nact; s += 4) {
        float4 v = wsp[(long)(b * NS + s) * (D_ / 4) + d4];
        acc.x += v.x; acc.y += v.y; acc.z += v.z; acc.w += v.w;
    }

    __shared__ float4 sm[4][64];
    sm[w][lane] = acc;
    __syncthreads();

    if (w == 0) {
        float4 a0 = sm[0][lane], a1 = sm[1][lane], a2 = sm[2][lane], a3 = sm[3][lane];
        const float inv = 1.0f / (float)len;
        float4 r;
        r.x = (a0.x + a1.x + a2.x + a3.x) * inv;
        r.y = (a0.y + a1.y + a2.y + a3.y) * inv;
        r.z = (a0.z + a1.z + a2.z + a3.z) * inv;
        r.w = (a0.w + a1.w + a2.w + a3.w) * inv;
        ((float4*)out)[(long)b * (D_ / 4) + d4] = r;
    }
}

extern "C" void kernel_launch(void* const* d_in, const int* in_sizes, int n_in,
                              void* d_out, int out_size, void* d_ws, size_t ws_size,
                              hipStream_t stream)
{
    const float* xs = (const float*)d_in[0];
    const void* xs_len = d_in[1];
    float* out = (float*)d_out;
    float* ws = (float*)d_ws;    // needs B_*NS*D_*4 = 4 MiB

    mp_partial<<<dim3(B_ * NS), dim3(256), 0, stream>>>(xs, xs_len, ws);
    mp_reduce<<<dim3(B_ * 4), dim3(256), 0, stream>>>(ws, xs_len, out);
}